// Round 1
// baseline (154.199 us; speedup 1.0000x reference)
//
#include <hip/hip_runtime.h>

// ACELoss3D: fused 19-point stencil (elastica) + region term + 3-way global sum.
// Shapes: (B=2, C=3, X=128, Y=128, Z=128) fp32, z innermost/contiguous.
// All derivative boundary cases in the reference are exactly clamped-index
// central differences (verified against the slice/concat construction).

static constexpr int   NTOT  = 6 * 128 * 128 * 128;   // 12,582,912
static constexpr float ALPHA_ = 0.001f;
static constexpr float MIU_   = 1.0f;
static constexpr float EPS_   = 1e-8f;

__device__ __forceinline__ void wave_reduce3(float& a, float& b, float& c) {
#pragma unroll
  for (int off = 32; off > 0; off >>= 1) {
    a += __shfl_down(a, off);
    b += __shfl_down(b, off);
    c += __shfl_down(c, off);
  }
}

__global__ __launch_bounds__(256) void ace_main(
    const float* __restrict__ pred, const float* __restrict__ truth,
    float* __restrict__ partials, int nthreads) {
  const int tid = threadIdx.x;
  float s1 = 0.f, s2 = 0.f, s3 = 0.f;

  for (int i = blockIdx.x * 256 + tid; i < NTOT; i += nthreads) {
    const int z     = i & 127;
    const int y     = (i >> 7) & 127;
    const int x     = (i >> 14) & 127;
    const int bcoff = (i >> 21) << 21;
    const float* __restrict__ b = pred + bcoff;

    const int zp = (z < 127) ? z + 1 : 127;
    const int zm = (z > 0)   ? z - 1 : 0;
    const int rC  = y << 7;
    const int rYp = ((y < 127) ? y + 1 : 127) << 7;
    const int rYm = ((y > 0)   ? y - 1 : 0)   << 7;
    const int pC  = x << 14;
    const int pXp = ((x < 127) ? x + 1 : 127) << 14;
    const int pXm = ((x > 0)   ? x - 1 : 0)   << 14;

    const float u0    = b[pC  + rC  + z ];
    const float uxp   = b[pXp + rC  + z ];
    const float uxm   = b[pXm + rC  + z ];
    const float uyp   = b[pC  + rYp + z ];
    const float uym   = b[pC  + rYm + z ];
    const float uzp   = b[pC  + rC  + zp];
    const float uzm   = b[pC  + rC  + zm];
    const float uxpyp = b[pXp + rYp + z ];
    const float uxmyp = b[pXm + rYp + z ];
    const float uxpym = b[pXp + rYm + z ];
    const float uxmym = b[pXm + rYm + z ];
    const float uxpzp = b[pXp + rC  + zp];
    const float uxmzp = b[pXm + rC  + zp];
    const float uxpzm = b[pXp + rC  + zm];
    const float uxmzm = b[pXm + rC  + zm];
    const float uypzp = b[pC  + rYp + zp];
    const float uymzp = b[pC  + rYm + zp];
    const float uypzm = b[pC  + rYp + zm];
    const float uymzm = b[pC  + rYm + zm];

    const float ci  = 0.5f * (uxp - uxm);
    const float cj  = 0.5f * (uyp - uym);
    const float ck  = 0.5f * (uzp - uzm);
    const float cii = uxp + uxm - 2.f * u0;
    const float cjj = uyp + uym - 2.f * u0;
    const float ckk = uzp + uzm - 2.f * u0;
    const float cij = 0.5f * ((uxpyp - uxmyp) - (uxpym - uxmym));
    const float cik = 0.5f * ((uxpzp - uxmzp) - (uxpzm - uxmzm));
    const float cjk = 0.5f * ((uypzp - uymzp) - (uypzm - uymzm));

    const float ci2 = ci * ci, cj2 = cj * cj, ck2 = ck * ck;
    const float ss  = ci2 + cj2 + ck2;
    const float length = sqrtf(EPS_ + ss);
    float curv = (1.f + ci2 + cj2) * ckk + (1.f + cj2 + ck2) * cii +
                 (1.f + ci2 + ck2) * cjj - 2.f * cik * cjk * cij;
    curv = fabsf(curv) / (sqrtf(1.f + ss) + EPS_);
    s3 += ALPHA_ + curv * curv * fabsf(length);

    const float t   = truth[i];
    const float tm1 = t - 1.f;
    s1 += u0 * (tm1 * tm1);
    s2 += (1.f - u0) * (t * t);
  }

  wave_reduce3(s1, s2, s3);
  __shared__ float l1[4], l2[4], l3[4];
  const int lane = tid & 63, wv = tid >> 6;
  if (lane == 0) { l1[wv] = s1; l2[wv] = s2; l3[wv] = s3; }
  __syncthreads();
  if (tid == 0) {
    partials[blockIdx.x * 3 + 0] = l1[0] + l1[1] + l1[2] + l1[3];
    partials[blockIdx.x * 3 + 1] = l2[0] + l2[1] + l2[2] + l2[3];
    partials[blockIdx.x * 3 + 2] = l3[0] + l3[1] + l3[2] + l3[3];
  }
}

__global__ __launch_bounds__(256) void ace_final(
    const float* __restrict__ partials, int nblocks, float* __restrict__ out) {
  const int tid = threadIdx.x;
  float s1 = 0.f, s2 = 0.f, s3 = 0.f;
  for (int i = tid; i < nblocks; i += 256) {
    s1 += partials[3 * i + 0];
    s2 += partials[3 * i + 1];
    s3 += partials[3 * i + 2];
  }
  wave_reduce3(s1, s2, s3);
  __shared__ float l1[4], l2[4], l3[4];
  const int lane = tid & 63, wv = tid >> 6;
  if (lane == 0) { l1[wv] = s1; l2[wv] = s2; l3[wv] = s3; }
  __syncthreads();
  if (tid == 0) {
    const float S1 = l1[0] + l1[1] + l1[2] + l1[3];
    const float S2 = l2[0] + l2[1] + l2[2] + l2[3];
    const float S3 = l3[0] + l3[1] + l3[2] + l3[3];
    out[0] = MIU_ * fabsf(S1) + fabsf(S2) + S3;   // region + elastica
  }
}

extern "C" void kernel_launch(void* const* d_in, const int* in_sizes, int n_in,
                              void* d_out, int out_size, void* d_ws, size_t ws_size,
                              hipStream_t stream) {
  const float* pred  = (const float*)d_in[0];   // y_pred
  const float* truth = (const float*)d_in[1];   // y_true
  float* out      = (float*)d_out;
  float* partials = (float*)d_ws;

  int nblocks = 3072;                                   // 12 blocks/CU, 16 elem/thread
  const size_t need = (size_t)nblocks * 3 * sizeof(float);
  if (ws_size < need) nblocks = (int)(ws_size / (3 * sizeof(float)));
  if (nblocks < 1) nblocks = 1;

  ace_main<<<nblocks, 256, 0, stream>>>(pred, truth, partials, nblocks * 256);
  ace_final<<<1, 256, 0, stream>>>(partials, nblocks, out);
}